// Round 1
// baseline (143.323 us; speedup 1.0000x reference)
//
#include <hip/hip_runtime.h>

typedef unsigned short u16;
typedef __attribute__((ext_vector_type(8))) __bf16 bf16x8;
typedef __attribute__((ext_vector_type(4))) float f32x4;
typedef __attribute__((ext_vector_type(8))) short short8;
typedef __attribute__((ext_vector_type(4))) u16 us4;

#define T_SEQ 1024
#define PROJW 1792
#define CDIM 512

__device__ __forceinline__ u16 f2bf(float f) {
  unsigned u = __float_as_uint(f);
  u += 0x7fff + ((u >> 16) & 1);
  return (u16)(u >> 16);
}

__global__ void cvt_x(const float4* __restrict__ x, u16* __restrict__ xb, int n4) {
  int i = blockIdx.x * 256 + threadIdx.x;
  if (i >= n4) return;
  float4 v = x[i];
  us4 o = { f2bf(v.x), f2bf(v.y), f2bf(v.z), f2bf(v.w) };
  *(us4*)&xb[i * 4] = o;
}

__global__ void prep_w(const float* __restrict__ Wq, const float* __restrict__ Wk,
                       const float* __restrict__ Wv, const float* __restrict__ Wqml,
                       const float* __restrict__ Wkml, const float* __restrict__ Wp,
                       const float* __restrict__ bq, const float* __restrict__ bk,
                       const float* __restrict__ bv, const float* __restrict__ bqml,
                       const float* __restrict__ bkml,
                       u16* __restrict__ Wcat, u16* __restrict__ Wpb, float* __restrict__ bcat) {
  int idx = blockIdx.x * 256 + threadIdx.x;
  const int NW = 1792 * 512;
  if (idx < NW) {
    int row = idx >> 9;
    float v;
    if (row < 512)       v = Wq[idx];
    else if (row < 1024) v = Wk[idx - 512 * 512];
    else if (row < 1536) v = Wv[idx - 1024 * 512];
    else if (row < 1664) v = Wqml[idx - 1536 * 512];
    else                 v = Wkml[idx - 1664 * 512];
    Wcat[idx] = f2bf(v);
    return;
  }
  int i2 = idx - NW;
  if (i2 < 512 * 512) { Wpb[i2] = f2bf(Wp[i2]); return; }
  int i3 = i2 - 512 * 512;
  if (i3 < 1792) {
    float v;
    if (i3 < 512)       v = bq[i3];
    else if (i3 < 1024) v = bk[i3 - 512];
    else if (i3 < 1536) v = bv[i3 - 1024];
    else if (i3 < 1664) v = bqml[i3 - 1536];
    else                v = bkml[i3 - 1664];
    bcat[i3] = v;
  }
}

template<bool OUT_BF16>
__global__ __launch_bounds__(256) void gemm_bt(
    const u16* __restrict__ A, int lda,
    const u16* __restrict__ Bw, int ldb,
    const float* __restrict__ bias,
    void* __restrict__ Cout, int ldc, int K) {
  __shared__ u16 As[64][40];
  __shared__ u16 Bs[64][40];
  const int tid = threadIdx.x;
  const int lane = tid & 63, w = tid >> 6;
  const int g = lane >> 4, c = lane & 15;
  const int m0 = blockIdx.y * 64, n0 = blockIdx.x * 64;
  const int wr = (w >> 1) * 32, wc = (w & 1) * 32;
  const int arow = tid >> 2, acol = (tid & 3) * 8;

  f32x4 acc[2][2] = {};
  for (int k0 = 0; k0 < K; k0 += 32) {
    short8 av = *(const short8*)&A[(size_t)(m0 + arow) * lda + k0 + acol];
    short8 bv = *(const short8*)&Bw[(size_t)(n0 + arow) * ldb + k0 + acol];
    *(short8*)&As[arow][acol] = av;
    *(short8*)&Bs[arow][acol] = bv;
    __syncthreads();
    bf16x8 a0 = *(const bf16x8*)&As[wr + c][g * 8];
    bf16x8 a1 = *(const bf16x8*)&As[wr + 16 + c][g * 8];
    bf16x8 b0 = *(const bf16x8*)&Bs[wc + c][g * 8];
    bf16x8 b1 = *(const bf16x8*)&Bs[wc + 16 + c][g * 8];
    acc[0][0] = __builtin_amdgcn_mfma_f32_16x16x32_bf16(a0, b0, acc[0][0], 0, 0, 0);
    acc[0][1] = __builtin_amdgcn_mfma_f32_16x16x32_bf16(a0, b1, acc[0][1], 0, 0, 0);
    acc[1][0] = __builtin_amdgcn_mfma_f32_16x16x32_bf16(a1, b0, acc[1][0], 0, 0, 0);
    acc[1][1] = __builtin_amdgcn_mfma_f32_16x16x32_bf16(a1, b1, acc[1][1], 0, 0, 0);
    __syncthreads();
  }
  for (int fm = 0; fm < 2; ++fm)
    for (int fn = 0; fn < 2; ++fn)
      for (int r = 0; r < 4; ++r) {
        int row = m0 + wr + fm * 16 + g * 4 + r;
        int col = n0 + wc + fn * 16 + c;
        float v = acc[fm][fn][r] + bias[col];
        if constexpr (OUT_BF16) ((u16*)Cout)[(size_t)row * ldc + col] = f2bf(v);
        else                    ((float*)Cout)[(size_t)row * ldc + col] = v;
      }
}

__device__ __forceinline__ bool visible(int q, int k, bool localMask) {
  int tq = (q < 2) ? 0 : ((q < 513) ? 2 * (q - 2) + 1 : 2 * (q - 513) + 2);
  int tk = (k < 2) ? 0 : ((k < 513) ? 2 * (k - 2) + 1 : 2 * (k - 513) + 2);
  bool vis = (tk <= tq);
  if (localMask && q >= 2 && k >= 2) {
    int jq = (q < 513) ? (q - 2) : (q - 513);
    int jk = (k < 513) ? (k - 2) : (k - 513);
    if (2 * jk + 1 < 2 * jq - 6) vis = false;
  }
  return vis;
}

__global__ __launch_bounds__(256) void attn_k(
    const u16* __restrict__ P, u16* __restrict__ Y,
    const float* __restrict__ mix_w, const float* __restrict__ bias_clip,
    const float* __restrict__ bias_clip_ml) {
  __shared__ u16 Ks[64][72];
  __shared__ u16 Vt[64][72];
  __shared__ u16 Ps[64][72];
  const int tid = threadIdx.x, lane = tid & 63, w = tid >> 6;
  const int g = lane >> 4, c = lane & 15;
  const int qt = blockIdx.x, h = blockIdx.y, b = blockIdx.z;
  const int npass = (h == 2 || h == 3) ? 2 : 1;
  const size_t baseP = (size_t)b * T_SEQ * PROJW;
  const int srow = tid >> 2, scol = (tid & 3) * 16;
  const int vcol = 1024 + h * 64;
  float yacc[4][4] = {};

  for (int pass = 0; pass < npass; ++pass) {
    int qcol, kcol;
    float kbias, wgt;
    bool localMask;
    if (pass == 0) {
      qcol = h * 64; kcol = 512 + h * 64;
      localMask = (h < 2);
      kbias = bias_clip[h];
      wgt = (h == 2 || h == 3) ? mix_w[(h - 2) * 2] : 1.0f;
    } else {
      int mh = h - 2;
      qcol = 1536 + mh * 64; kcol = 1664 + mh * 64;
      localMask = true;
      kbias = bias_clip_ml[mh];
      wgt = mix_w[mh * 2 + 1];
    }
    const int qrow = qt * 64 + w * 16 + c;
    bf16x8 aq0 = *(const bf16x8*)&P[baseP + (size_t)qrow * PROJW + qcol + g * 8];
    bf16x8 aq1 = *(const bf16x8*)&P[baseP + (size_t)qrow * PROJW + qcol + 32 + g * 8];

    float m[4], l[4];
    f32x4 o[4] = {};
    for (int r = 0; r < 4; ++r) { m[r] = -1e30f; l[r] = 0.0f; }

    for (int kt = 0; kt < 16; ++kt) {
      const int k0 = kt * 64;
      __syncthreads();
      {
        const u16* ksrc = &P[baseP + (size_t)(k0 + srow) * PROJW + kcol + scol];
        short8 kv0 = *(const short8*)ksrc;
        short8 kv1 = *(const short8*)(ksrc + 8);
        *(short8*)&Ks[srow][scol] = kv0;
        *(short8*)&Ks[srow][scol + 8] = kv1;
        const u16* vsrc = &P[baseP + (size_t)(k0 + srow) * PROJW + vcol + scol];
        short8 v0 = *(const short8*)vsrc;
        short8 v1 = *(const short8*)(vsrc + 8);
#pragma unroll
        for (int j = 0; j < 8; ++j) {
          Vt[scol + j][srow] = (u16)v0[j];
          Vt[scol + 8 + j][srow] = (u16)v1[j];
        }
      }
      __syncthreads();

      float s[4][4];
#pragma unroll
      for (int cb = 0; cb < 4; ++cb) {
        f32x4 accs = {};
        bf16x8 bk0 = *(const bf16x8*)&Ks[cb * 16 + c][g * 8];
        bf16x8 bk1 = *(const bf16x8*)&Ks[cb * 16 + c][32 + g * 8];
        accs = __builtin_amdgcn_mfma_f32_16x16x32_bf16(aq0, bk0, accs, 0, 0, 0);
        accs = __builtin_amdgcn_mfma_f32_16x16x32_bf16(aq1, bk1, accs, 0, 0, 0);
#pragma unroll
        for (int r = 0; r < 4; ++r) s[cb][r] = accs[r] * 0.125f;
      }
      const int rowg0 = qt * 64 + w * 16 + g * 4;
#pragma unroll
      for (int cb = 0; cb < 4; ++cb) {
        int colg = k0 + cb * 16 + c;
        float addb = (colg == 1) ? kbias : 0.0f;
#pragma unroll
        for (int r = 0; r < 4; ++r) {
          bool vis = visible(rowg0 + r, colg, localMask);
          s[cb][r] = vis ? (s[cb][r] + addb) : -1e9f;
        }
      }
#pragma unroll
      for (int r = 0; r < 4; ++r) {
        float rmax = fmaxf(fmaxf(s[0][r], s[1][r]), fmaxf(s[2][r], s[3][r]));
        for (int off = 1; off < 16; off <<= 1)
          rmax = fmaxf(rmax, __shfl_xor(rmax, off));
        float mnew = fmaxf(m[r], rmax);
        float fr = __expf(m[r] - mnew);
        float psum = 0.0f;
#pragma unroll
        for (int cb = 0; cb < 4; ++cb) {
          float p = __expf(s[cb][r] - mnew);
          s[cb][r] = p;
          psum += p;
        }
        for (int off = 1; off < 16; off <<= 1)
          psum += __shfl_xor(psum, off);
        l[r] = l[r] * fr + psum;
        m[r] = mnew;
#pragma unroll
        for (int db = 0; db < 4; ++db) o[db][r] *= fr;
      }
#pragma unroll
      for (int cb = 0; cb < 4; ++cb)
#pragma unroll
        for (int r = 0; r < 4; ++r)
          Ps[w * 16 + g * 4 + r][cb * 16 + c] = f2bf(s[cb][r]);
      asm volatile("s_waitcnt lgkmcnt(0)" ::: "memory");
#pragma unroll
      for (int ks = 0; ks < 2; ++ks) {
        bf16x8 ap = *(const bf16x8*)&Ps[w * 16 + c][ks * 32 + g * 8];
#pragma unroll
        for (int db = 0; db < 4; ++db) {
          bf16x8 bv = *(const bf16x8*)&Vt[db * 16 + c][ks * 32 + g * 8];
          o[db] = __builtin_amdgcn_mfma_f32_16x16x32_bf16(ap, bv, o[db], 0, 0, 0);
        }
      }
    }
#pragma unroll
    for (int db = 0; db < 4; ++db)
#pragma unroll
      for (int r = 0; r < 4; ++r)
        yacc[db][r] += wgt * o[db][r] / l[r];
  }
  const int rowg0 = qt * 64 + w * 16 + g * 4;
#pragma unroll
  for (int db = 0; db < 4; ++db)
#pragma unroll
    for (int r = 0; r < 4; ++r) {
      int row = rowg0 + r;
      int col = h * 64 + db * 16 + c;
      Y[((size_t)b * T_SEQ + row) * CDIM + col] = f2bf(yacc[db][r]);
    }
}

extern "C" void kernel_launch(void* const* d_in, const int* in_sizes, int n_in,
                              void* d_out, int out_size, void* d_ws, size_t ws_size,
                              hipStream_t stream) {
  const float* x     = (const float*)d_in[0];
  const float* Wq    = (const float*)d_in[2];
  const float* bq    = (const float*)d_in[3];
  const float* Wk    = (const float*)d_in[4];
  const float* bk    = (const float*)d_in[5];
  const float* Wv    = (const float*)d_in[6];
  const float* bv    = (const float*)d_in[7];
  const float* Wqml  = (const float*)d_in[8];
  const float* bqml  = (const float*)d_in[9];
  const float* Wkml  = (const float*)d_in[10];
  const float* bkml  = (const float*)d_in[11];
  const float* mixw  = (const float*)d_in[12];
  const float* Wp    = (const float*)d_in[13];
  const float* bp    = (const float*)d_in[14];
  const float* bclip = (const float*)d_in[15];
  const float* bclipml = (const float*)d_in[16];

  u16* xb   = (u16*)d_ws;              // 4096*512 bf16
  u16* Wcat = xb + 4096 * 512;         // 1792*512 bf16
  u16* Wpb  = Wcat + 1792 * 512;       // 512*512 bf16
  u16* Ybuf = Wpb + 512 * 512;         // 4096*512 bf16
  float* bcat = (float*)(Ybuf + 4096 * 512);  // 1792 f32 (pad 2048)
  u16* Pbuf = (u16*)(bcat + 2048);     // 4096*1792 bf16

  cvt_x<<<2048, 256, 0, stream>>>((const float4*)x, xb, 524288);
  prep_w<<<4615, 256, 0, stream>>>(Wq, Wk, Wv, Wqml, Wkml, Wp,
                                   bq, bk, bv, bqml, bkml, Wcat, Wpb, bcat);
  gemm_bt<true><<<dim3(28, 64), 256, 0, stream>>>(xb, 512, Wcat, 512, bcat,
                                                  (void*)Pbuf, 1792, 512);
  attn_k<<<dim3(16, 8, 4), 256, 0, stream>>>(Pbuf, Ybuf, mixw, bclip, bclipml);
  gemm_bt<false><<<dim3(8, 64), 256, 0, stream>>>(Ybuf, 512, Wpb, 512, bp,
                                                  (void*)d_out, 512, 512);
}

// Round 2
// 98.403 us; speedup vs baseline: 1.4565x; 1.4565x over previous
//
#include <hip/hip_runtime.h>

typedef unsigned short u16;
typedef __attribute__((ext_vector_type(8))) __bf16 bf16x8;
typedef __attribute__((ext_vector_type(4))) float f32x4;
typedef __attribute__((ext_vector_type(8))) short short8;
typedef __attribute__((ext_vector_type(4))) u16 us4;

#define T_SEQ 1024
#define PROJW 1280   // P buffer row: Q(512) K(512) QML(128) KML(128); V goes to Vtb

__device__ __forceinline__ u16 f2bf(float f) {
  unsigned u = __float_as_uint(f);
  u += 0x7fff + ((u >> 16) & 1);
  return (u16)(u >> 16);
}

// per-qtile bitmask of kv-tiles containing any visible key (derived from the
// interleaved-temporal causal mask and the RECEP=4 sliding window; exact).
__constant__ u16 GLOB_M[16] = {0x0101,0x0303,0x0707,0x0F0F,0x1F1F,0x3F3F,0x7F7F,0xFFFF,
                               0xFFFF,0x0307,0x070F,0x0F1F,0x1F3F,0x3F7F,0x7FFF,0xFFFF};
__constant__ u16 LOC_M[16]  = {0x0101,0x0303,0x0607,0x0C0D,0x1819,0x3031,0x6061,0xC0C1,
                               0x8183,0x0307,0x060F,0x0C1D,0x1839,0x3071,0x60E1,0xC1C1};

__global__ void cvt_x(const float4* __restrict__ x, u16* __restrict__ xb, int n4) {
  int i = blockIdx.x * 256 + threadIdx.x;
  if (i >= n4) return;
  float4 v = x[i];
  us4 o = { f2bf(v.x), f2bf(v.y), f2bf(v.z), f2bf(v.w) };
  *(us4*)&xb[i * 4] = o;
}

__global__ void prep_w(const float* __restrict__ Wq, const float* __restrict__ Wk,
                       const float* __restrict__ Wv, const float* __restrict__ Wqml,
                       const float* __restrict__ Wkml, const float* __restrict__ Wp,
                       const float* __restrict__ bq, const float* __restrict__ bk,
                       const float* __restrict__ bv, const float* __restrict__ bqml,
                       const float* __restrict__ bkml,
                       u16* __restrict__ Wcat, u16* __restrict__ Wpx, float* __restrict__ bcat) {
  int idx = blockIdx.x * 256 + threadIdx.x;
  const int NW = 1792 * 512;
  if (idx < NW) {
    int row = idx >> 9;
    float v;
    if (row < 512)       v = Wq[idx];
    else if (row < 1024) v = Wk[idx - 512 * 512];
    else if (row < 1536) v = Wv[idx - 1024 * 512];
    else if (row < 1664) v = Wqml[idx - 1536 * 512];
    else                 v = Wkml[idx - 1664 * 512];
    Wcat[idx] = f2bf(v);
    return;
  }
  int i2 = idx - NW;
  if (i2 < 512 * 640) {
    int n = i2 / 640, k2 = i2 - n * 640;
    float v = (k2 < 512) ? Wp[n * 512 + k2] : Wp[n * 512 + k2 - 384];
    Wpx[i2] = f2bf(v);
    return;
  }
  int i3 = i2 - 512 * 640;
  if (i3 < 1792) {
    float v;
    if (i3 < 512)       v = bq[i3];
    else if (i3 < 1024) v = bk[i3 - 512];
    else if (i3 < 1536) v = bv[i3 - 1024];
    else if (i3 < 1664) v = bqml[i3 - 1536];
    else                v = bkml[i3 - 1664];
    bcat[i3] = v;
  }
}

// QKV projection: C = x @ Wcat^T + bcat. Q,K,QML,KML -> Pout (row 1280);
// V (cols 1024..1535) -> Vtb transposed [b][d(512)][t(1024)].
__global__ __launch_bounds__(256) void gemm_qkv(
    const u16* __restrict__ A, const u16* __restrict__ Bw,
    const float* __restrict__ bias, u16* __restrict__ Pout, u16* __restrict__ Vtb) {
  __shared__ u16 As[64][40];
  __shared__ u16 Bs[64][40];
  const int tid = threadIdx.x;
  const int lane = tid & 63, w = tid >> 6;
  const int g = lane >> 4, c = lane & 15;
  const int m0 = blockIdx.y * 64, n0 = blockIdx.x * 64;
  const int wr = (w >> 1) * 32, wc = (w & 1) * 32;
  const int arow = tid >> 2, acol = (tid & 3) * 8;

  f32x4 acc[2][2] = {};
  for (int k0 = 0; k0 < 512; k0 += 32) {
    short8 av = *(const short8*)&A[(size_t)(m0 + arow) * 512 + k0 + acol];
    short8 bv = *(const short8*)&Bw[(size_t)(n0 + arow) * 512 + k0 + acol];
    *(short8*)&As[arow][acol] = av;
    *(short8*)&Bs[arow][acol] = bv;
    __syncthreads();
    bf16x8 a0 = *(const bf16x8*)&As[wr + c][g * 8];
    bf16x8 a1 = *(const bf16x8*)&As[wr + 16 + c][g * 8];
    bf16x8 b0 = *(const bf16x8*)&Bs[wc + c][g * 8];
    bf16x8 b1 = *(const bf16x8*)&Bs[wc + 16 + c][g * 8];
    acc[0][0] = __builtin_amdgcn_mfma_f32_16x16x32_bf16(a0, b0, acc[0][0], 0, 0, 0);
    acc[0][1] = __builtin_amdgcn_mfma_f32_16x16x32_bf16(a0, b1, acc[0][1], 0, 0, 0);
    acc[1][0] = __builtin_amdgcn_mfma_f32_16x16x32_bf16(a1, b0, acc[1][0], 0, 0, 0);
    acc[1][1] = __builtin_amdgcn_mfma_f32_16x16x32_bf16(a1, b1, acc[1][1], 0, 0, 0);
    __syncthreads();
  }
  if (n0 >= 1024 && n0 < 1536) {
    // V: transposed write, pack 4 consecutive t as one 8B store
    for (int fm = 0; fm < 2; ++fm)
      for (int fn = 0; fn < 2; ++fn) {
        int row = m0 + wr + fm * 16 + g * 4;
        int col = n0 + wc + fn * 16 + c;
        float bb = bias[col];
        int d = col - 1024;
        int bidx = row >> 10, t = row & 1023;
        us4 pack = { f2bf(acc[fm][fn][0] + bb), f2bf(acc[fm][fn][1] + bb),
                     f2bf(acc[fm][fn][2] + bb), f2bf(acc[fm][fn][3] + bb) };
        *(us4*)&Vtb[((size_t)bidx * 512 + d) * 1024 + t] = pack;
      }
  } else {
    for (int fm = 0; fm < 2; ++fm)
      for (int fn = 0; fn < 2; ++fn)
        for (int r = 0; r < 4; ++r) {
          int row = m0 + wr + fm * 16 + g * 4 + r;
          int col = n0 + wc + fn * 16 + c;
          int pcol = (col < 1024) ? col : col - 512;
          Pout[(size_t)row * PROJW + pcol] = f2bf(acc[fm][fn][r] + bias[col]);
        }
  }
}

// generic C[m][n] = A[m][:] . Bw[n][:] + bias[n]
template<bool OUT_BF16>
__global__ __launch_bounds__(256) void gemm_bt(
    const u16* __restrict__ A, int lda,
    const u16* __restrict__ Bw, int ldb,
    const float* __restrict__ bias,
    void* __restrict__ Cout, int ldc, int K) {
  __shared__ u16 As[64][40];
  __shared__ u16 Bs[64][40];
  const int tid = threadIdx.x;
  const int lane = tid & 63, w = tid >> 6;
  const int g = lane >> 4, c = lane & 15;
  const int m0 = blockIdx.y * 64, n0 = blockIdx.x * 64;
  const int wr = (w >> 1) * 32, wc = (w & 1) * 32;
  const int arow = tid >> 2, acol = (tid & 3) * 8;

  f32x4 acc[2][2] = {};
  for (int k0 = 0; k0 < K; k0 += 32) {
    short8 av = *(const short8*)&A[(size_t)(m0 + arow) * lda + k0 + acol];
    short8 bv = *(const short8*)&Bw[(size_t)(n0 + arow) * ldb + k0 + acol];
    *(short8*)&As[arow][acol] = av;
    *(short8*)&Bs[arow][acol] = bv;
    __syncthreads();
    bf16x8 a0 = *(const bf16x8*)&As[wr + c][g * 8];
    bf16x8 a1 = *(const bf16x8*)&As[wr + 16 + c][g * 8];
    bf16x8 b0 = *(const bf16x8*)&Bs[wc + c][g * 8];
    bf16x8 b1 = *(const bf16x8*)&Bs[wc + 16 + c][g * 8];
    acc[0][0] = __builtin_amdgcn_mfma_f32_16x16x32_bf16(a0, b0, acc[0][0], 0, 0, 0);
    acc[0][1] = __builtin_amdgcn_mfma_f32_16x16x32_bf16(a0, b1, acc[0][1], 0, 0, 0);
    acc[1][0] = __builtin_amdgcn_mfma_f32_16x16x32_bf16(a1, b0, acc[1][0], 0, 0, 0);
    acc[1][1] = __builtin_amdgcn_mfma_f32_16x16x32_bf16(a1, b1, acc[1][1], 0, 0, 0);
    __syncthreads();
  }
  for (int fm = 0; fm < 2; ++fm)
    for (int fn = 0; fn < 2; ++fn)
      for (int r = 0; r < 4; ++r) {
        int row = m0 + wr + fm * 16 + g * 4 + r;
        int col = n0 + wc + fn * 16 + c;
        float v = acc[fm][fn][r] + bias[col];
        if constexpr (OUT_BF16) ((u16*)Cout)[(size_t)row * ldc + col] = f2bf(v);
        else                    ((float*)Cout)[(size_t)row * ldc + col] = v;
      }
}

__device__ __forceinline__ bool visible(int q, int k, bool localMask) {
  int tq = (q < 2) ? 0 : ((q < 513) ? 2 * (q - 2) + 1 : 2 * (q - 513) + 2);
  int tk = (k < 2) ? 0 : ((k < 513) ? 2 * (k - 2) + 1 : 2 * (k - 513) + 2);
  bool vis = (tk <= tq);
  if (localMask && q >= 2 && k >= 2) {
    int jq = (q < 513) ? (q - 2) : (q - 513);
    int jk = (k < 513) ? (k - 2) : (k - 513);
    if (jk < jq - 3) vis = false;
  }
  return vis;
}

// grid (16 qt, 10 units, 4 b). unit 0..7 = main heads (local for 0,1; causal
// else; heads 2,3 scaled by mix_w[:,0]); unit 8,9 = ml local passes scaled by
// mix_w[:,1], written to Y cols 512..639 (folded into proj via extended Wpx).
__global__ __launch_bounds__(256) void attn_k(
    const u16* __restrict__ P, const u16* __restrict__ Vtb, u16* __restrict__ Y,
    const float* __restrict__ mix_w, const float* __restrict__ bias_clip,
    const float* __restrict__ bias_clip_ml) {
  __shared__ u16 Ks[2][64][72];
  __shared__ u16 Vs[2][64][72];
  __shared__ u16 Ps[64][72];
  const int tid = threadIdx.x, lane = tid & 63, w = tid >> 6;
  const int g = lane >> 4, c = lane & 15;
  const int qt = blockIdx.x, u = blockIdx.y, b = blockIdx.z;

  int qcol, kcol, vsel, outcol;
  bool localMask;
  float kbias, wgt;
  if (u < 8) {
    qcol = u * 64; kcol = 512 + u * 64; vsel = u; outcol = u * 64;
    localMask = (u < 2);
    kbias = bias_clip[u];
    wgt = (u == 2 || u == 3) ? mix_w[(u - 2) * 2] : 1.0f;
  } else {
    int mh = u - 8;
    qcol = 1024 + mh * 64; kcol = 1152 + mh * 64; vsel = 2 + mh; outcol = 512 + mh * 64;
    localMask = true;
    kbias = bias_clip_ml[mh];
    wgt = mix_w[mh * 2 + 1];
  }
  unsigned mask = localMask ? (unsigned)LOC_M[qt] : (unsigned)GLOB_M[qt];
  const size_t baseP = (size_t)b * T_SEQ * PROJW;
  const u16* __restrict__ Vbase = Vtb + ((size_t)b * 512 + vsel * 64) * 1024;
  const int srow = tid >> 2, scol = (tid & 3) * 16;

  const int qrow = qt * 64 + w * 16 + c;
  bf16x8 aq0 = *(const bf16x8*)&P[baseP + (size_t)qrow * PROJW + qcol + g * 8];
  bf16x8 aq1 = *(const bf16x8*)&P[baseP + (size_t)qrow * PROJW + qcol + 32 + g * 8];

  float m[4], l[4];
  f32x4 o[4] = {};
  for (int r = 0; r < 4; ++r) { m[r] = -1e30f; l[r] = 0.0f; }

  unsigned rem = mask;
  int kt = __ffs(rem) - 1; rem &= rem - 1;
  short8 kr0, kr1, vr0, vr1;
  {
    const u16* ks = &P[baseP + (size_t)(kt * 64 + srow) * PROJW + kcol + scol];
    kr0 = *(const short8*)ks; kr1 = *(const short8*)(ks + 8);
    const u16* vsrc = Vbase + (size_t)srow * 1024 + kt * 64 + scol;
    vr0 = *(const short8*)vsrc; vr1 = *(const short8*)(vsrc + 8);
  }
  int cur = 0;
  *(short8*)&Ks[0][srow][scol] = kr0;
  *(short8*)&Ks[0][srow][scol + 8] = kr1;
  *(short8*)&Vs[0][srow][scol] = vr0;
  *(short8*)&Vs[0][srow][scol + 8] = vr1;
  __syncthreads();

  while (true) {
    int ktn = -1;
    if (rem) { ktn = __ffs(rem) - 1; rem &= rem - 1; }
    if (ktn >= 0) {
      const u16* ks = &P[baseP + (size_t)(ktn * 64 + srow) * PROJW + kcol + scol];
      kr0 = *(const short8*)ks; kr1 = *(const short8*)(ks + 8);
      const u16* vsrc = Vbase + (size_t)srow * 1024 + ktn * 64 + scol;
      vr0 = *(const short8*)vsrc; vr1 = *(const short8*)(vsrc + 8);
    }

    const int k0 = kt * 64;
    float s[4][4];
#pragma unroll
    for (int cb = 0; cb < 4; ++cb) {
      f32x4 accs = {};
      bf16x8 bk0 = *(const bf16x8*)&Ks[cur][cb * 16 + c][g * 8];
      bf16x8 bk1 = *(const bf16x8*)&Ks[cur][cb * 16 + c][32 + g * 8];
      accs = __builtin_amdgcn_mfma_f32_16x16x32_bf16(aq0, bk0, accs, 0, 0, 0);
      accs = __builtin_amdgcn_mfma_f32_16x16x32_bf16(aq1, bk1, accs, 0, 0, 0);
#pragma unroll
      for (int r = 0; r < 4; ++r) s[cb][r] = accs[r] * 0.125f;
    }
    const int rowg0 = qt * 64 + w * 16 + g * 4;
#pragma unroll
    for (int cb = 0; cb < 4; ++cb) {
      int colg = k0 + cb * 16 + c;
      float addb = (colg == 1) ? kbias : 0.0f;
#pragma unroll
      for (int r = 0; r < 4; ++r) {
        bool vis = visible(rowg0 + r, colg, localMask);
        s[cb][r] = vis ? (s[cb][r] + addb) : -1e9f;
      }
    }
#pragma unroll
    for (int r = 0; r < 4; ++r) {
      float rmax = fmaxf(fmaxf(s[0][r], s[1][r]), fmaxf(s[2][r], s[3][r]));
      for (int off = 1; off < 16; off <<= 1)
        rmax = fmaxf(rmax, __shfl_xor(rmax, off));
      float mnew = fmaxf(m[r], rmax);
      float fr = __expf(m[r] - mnew);
      float psum = 0.0f;
#pragma unroll
      for (int cb = 0; cb < 4; ++cb) {
        float p = __expf(s[cb][r] - mnew);
        s[cb][r] = p;
        psum += p;
      }
      for (int off = 1; off < 16; off <<= 1)
        psum += __shfl_xor(psum, off);
      l[r] = l[r] * fr + psum;
      m[r] = mnew;
#pragma unroll
      for (int db = 0; db < 4; ++db) o[db][r] *= fr;
    }
#pragma unroll
    for (int cb = 0; cb < 4; ++cb)
#pragma unroll
      for (int r = 0; r < 4; ++r)
        Ps[w * 16 + g * 4 + r][cb * 16 + c] = f2bf(s[cb][r]);
    asm volatile("s_waitcnt lgkmcnt(0)" ::: "memory");
    __builtin_amdgcn_sched_barrier(0);
#pragma unroll
    for (int ks2 = 0; ks2 < 2; ++ks2) {
      bf16x8 ap = *(const bf16x8*)&Ps[w * 16 + c][ks2 * 32 + g * 8];
#pragma unroll
      for (int db = 0; db < 4; ++db) {
        bf16x8 bv = *(const bf16x8*)&Vs[cur][db * 16 + c][ks2 * 32 + g * 8];
        o[db] = __builtin_amdgcn_mfma_f32_16x16x32_bf16(ap, bv, o[db], 0, 0, 0);
      }
    }

    if (ktn < 0) break;
    __syncthreads();   // all waves done with buf[cur^1] reads (prev iter)
    *(short8*)&Ks[cur ^ 1][srow][scol] = kr0;
    *(short8*)&Ks[cur ^ 1][srow][scol + 8] = kr1;
    *(short8*)&Vs[cur ^ 1][srow][scol] = vr0;
    *(short8*)&Vs[cur ^ 1][srow][scol + 8] = vr1;
    __syncthreads();   // buf[cur^1] ready
    cur ^= 1; kt = ktn;
  }

  const int rowg0 = qt * 64 + w * 16 + g * 4;
#pragma unroll
  for (int db = 0; db < 4; ++db)
#pragma unroll
    for (int r = 0; r < 4; ++r) {
      int row = rowg0 + r;
      int col = outcol + db * 16 + c;
      Y[((size_t)b * T_SEQ + row) * 640 + col] = f2bf(wgt * o[db][r] / l[r]);
    }
}

extern "C" void kernel_launch(void* const* d_in, const int* in_sizes, int n_in,
                              void* d_out, int out_size, void* d_ws, size_t ws_size,
                              hipStream_t stream) {
  const float* x     = (const float*)d_in[0];
  const float* Wq    = (const float*)d_in[2];
  const float* bq    = (const float*)d_in[3];
  const float* Wk    = (const float*)d_in[4];
  const float* bk    = (const float*)d_in[5];
  const float* Wv    = (const float*)d_in[6];
  const float* bv    = (const float*)d_in[7];
  const float* Wqml  = (const float*)d_in[8];
  const float* bqml  = (const float*)d_in[9];
  const float* Wkml  = (const float*)d_in[10];
  const float* bkml  = (const float*)d_in[11];
  const float* mixw  = (const float*)d_in[12];
  const float* Wp    = (const float*)d_in[13];
  const float* bp    = (const float*)d_in[14];
  const float* bclip = (const float*)d_in[15];
  const float* bclipml = (const float*)d_in[16];

  u16* xb   = (u16*)d_ws;                  // 4096*512
  u16* Wcat = xb + 4096 * 512;             // 1792*512
  u16* Wpx  = Wcat + 1792 * 512;           // 512*640 (Wp | Wp[:,128:256])
  u16* Ybuf = Wpx + 512 * 640;             // 4096*640
  u16* Vtb  = Ybuf + 4096 * 640;           // 4*512*1024 (V transposed)
  u16* Pbuf = Vtb + 4 * 512 * 1024;        // 4096*1280
  float* bcat = (float*)(Pbuf + 4096 * 1280);  // 1792 f32

  cvt_x<<<2048, 256, 0, stream>>>((const float4*)x, xb, 524288);
  prep_w<<<4871, 256, 0, stream>>>(Wq, Wk, Wv, Wqml, Wkml, Wp,
                                   bq, bk, bv, bqml, bkml, Wcat, Wpx, bcat);
  gemm_qkv<<<dim3(28, 64), 256, 0, stream>>>(xb, Wcat, bcat, Pbuf, Vtb);
  attn_k<<<dim3(16, 10, 4), 256, 0, stream>>>(Pbuf, Vtb, Ybuf, mixw, bclip, bclipml);
  gemm_bt<false><<<dim3(8, 64), 256, 0, stream>>>(Ybuf, 640, Wpx, 640, bp,
                                                  (void*)d_out, 512, 640);
}